// Round 1
// baseline (262.462 us; speedup 1.0000x reference)
//
#include <hip/hip_runtime.h>
#include <hip/hip_bf16.h>

// Problem constants (from reference):
// inputs: (B=8, C=2, D=96, H=64, W=64) f32
// weight/bias: (F=8, C=2, d=3, h=60, w=64) f32
// out: (B=8, F=8, Dout=94, h=60, w=64) f32
#define B_ 8
#define C_ 2
#define D_ 96
#define H_ 64
#define W_ 64
#define F_ 8
#define KD 3
#define h_ 60
#define w_ 64
#define Dout_ 94

// Each block: one (b, f, do) output plane of 60x64.
// 256 threads = 64 columns x 4 row-groups of 15 rows each.
__global__ __launch_bounds__(256) void lc3d_kernel(
    const float* __restrict__ in, const float* __restrict__ wt,
    const float* __restrict__ bs, float* __restrict__ out)
{
    const int blk  = blockIdx.x;
    const int dout = blk % Dout_;
    const int f    = (blk / Dout_) % F_;
    const int b    = blk / (Dout_ * F_);

    const int tid = threadIdx.x;
    const int ww  = tid & 63;        // column 0..63
    const int rg  = tid >> 6;        // row group 0..3
    const int i0  = rg * 15;         // first of this thread's 15 rows

    float acc[15];
#pragma unroll
    for (int r = 0; r < 15; ++r) acc[r] = 0.f;

    // R[i][x] = sum_{c,z} ( S2 * weight + bias ),
    // S2[i] = sum_{j=0..4} in[b,c,dout+z, i+j, x]
    for (int c = 0; c < C_; ++c) {
#pragma unroll
        for (int z = 0; z < KD; ++z) {
            const float* ip = in + ((size_t)(((b*C_ + c)*D_ + (dout + z)))*H_)*W_ + ww;
            const float* wp = wt + ((size_t)(((f*C_ + c)*KD + z))*h_ + i0)*w_ + ww;
            const float* bp = bs + ((size_t)(((f*C_ + c)*KD + z))*h_ + i0)*w_ + ww;

            float v[19];
#pragma unroll
            for (int j = 0; j < 19; ++j) v[j] = ip[(i0 + j)*W_];

#pragma unroll
            for (int r = 0; r < 15; ++r) {
                float s = v[r] + v[r+1] + v[r+2] + v[r+3] + v[r+4];
                acc[r] += s * wp[r*w_] + bp[r*w_];
            }
        }
    }

    // Stage R plane into LDS for the 3x3 box sum.
    __shared__ float lds[h_ * w_];   // 15360 B
#pragma unroll
    for (int r = 0; r < 15; ++r) lds[(i0 + r)*w_ + ww] = acc[r];
    __syncthreads();

    float* op = out + ((size_t)((b*F_ + f)*Dout_ + dout))*(h_*w_) + ww;
#pragma unroll
    for (int r = 0; r < 15; ++r) {
        const int y = i0 + r;
        float sum = 0.f;
#pragma unroll
        for (int dy = -1; dy <= 1; ++dy) {
            const int yy = y + dy;
            if (yy < 0 || yy >= h_) continue;
#pragma unroll
            for (int dx = -1; dx <= 1; ++dx) {
                const int xx = ww + dx;
                if (xx < 0 || xx >= w_) continue;
                sum += lds[yy*w_ + xx];
            }
        }
        const float v = 0.25f * sum;
        op[y*w_] = (v > 0.f) ? v : 0.2f * v;
    }
}

extern "C" void kernel_launch(void* const* d_in, const int* in_sizes, int n_in,
                              void* d_out, int out_size, void* d_ws, size_t ws_size,
                              hipStream_t stream) {
    const float* in = (const float*)d_in[0];
    const float* wt = (const float*)d_in[1];
    const float* bs = (const float*)d_in[2];
    float* out = (float*)d_out;

    dim3 grid(B_ * F_ * Dout_);   // 6016 blocks, one per (b,f,do)
    dim3 block(256);
    lc3d_kernel<<<grid, block, 0, stream>>>(in, wt, bs, out);
}

// Round 2
// 168.414 us; speedup vs baseline: 1.5584x; 1.5584x over previous
//
#include <hip/hip_runtime.h>

// Problem constants:
// inputs: (B=8, C=2, D=96, H=64, W=64) f32
// weight/bias: (F=8, C=2, d=3, h=60, w=64) f32
// out: (B=8, F=8, Dout=94, h=60, w=64) f32
#define B_ 8
#define C_ 2
#define D_ 96
#define H_ 64
#define W_ 64
#define F_ 8
#define KD 3
#define h_ 60
#define Dout_ 94
#define PLANE (h_ * W_)          // 3840 floats per (h,w) plane
#define NCH (PLANE / 4)          // 960 float4 chunks per plane
#define TD 8                     // douts per block in k_main
#define NTILE ((Dout_ + TD - 1) / TD)  // 12
#define S2_FLOATS ((size_t)B_ * C_ * D_ * PLANE)  // 5,898,240

// ---------------------------------------------------------------------------
// Kernel 1: S2[b,c,p,i,x] = sum_{j=0..4} in[b,c,p,i+j,x]   (vertical 5-sum)
// One block per (b,c,p) plane. Stage 64x64 plane in LDS, then 5-tap sums.
// ---------------------------------------------------------------------------
__global__ __launch_bounds__(256) void k_s2(const float* __restrict__ in,
                                            float* __restrict__ s2) {
    const int bx = blockIdx.x;  // (b*C+c)*D + p
    const float4* ip4 = (const float4*)(in + (size_t)bx * (H_ * W_));
    float4* op4 = (float4*)(s2 + (size_t)bx * PLANE);
    __shared__ float4 lds[H_ * 16];  // 64 rows x 16 float4 = 16 KB
    const int tid = threadIdx.x;
#pragma unroll
    for (int k = 0; k < 4; ++k) lds[tid + 256 * k] = ip4[tid + 256 * k];
    __syncthreads();
#pragma unroll
    for (int k = 0; k < 4; ++k) {
        const int e = tid + 256 * k;
        if (e < NCH) {
            const int row = e >> 4, col = e & 15;
            float4 s = lds[row * 16 + col];
#pragma unroll
            for (int j = 1; j < 5; ++j) {
                const float4 v = lds[(row + j) * 16 + col];
                s.x += v.x; s.y += v.y; s.z += v.z; s.w += v.w;
            }
            op4[e] = s;
        }
    }
}

// Horizontal 3-tap sum via lane shuffles. Lane layout: within each 16-lane
// group all lanes share a row; col4 = lane & 15. Boundary cols -> zero.
__device__ __forceinline__ float4 hsum3(float4 V, int col4) {
    const int lane = threadIdx.x & 63;
    float lw = __shfl(V.w, (lane + 63) & 63, 64);  // left neighbor's .w
    float rx = __shfl(V.x, (lane + 1) & 63, 64);   // right neighbor's .x
    if (col4 == 0) lw = 0.f;
    if (col4 == 15) rx = 0.f;
    float4 o;
    o.x = lw + V.x + V.y;
    o.y = V.x + V.y + V.z;
    o.z = V.y + V.z + V.w;
    o.w = V.z + V.w + rx;
    return o;
}

// ---------------------------------------------------------------------------
// Kernel 2: BoxBS[f,y,x] = Box3x3( sum_{c,z} bias[f,c,z,y,x] )  (unscaled)
// One block per f.
// ---------------------------------------------------------------------------
__global__ __launch_bounds__(256) void k_boxbs(const float* __restrict__ bs,
                                               float* __restrict__ bb) {
    const int f = blockIdx.x;
    const int tid = threadIdx.x;
    __shared__ float4 R[62 * 16];  // padded rows 0 and 61 are zero
    if (tid < 32) {
        const int r = (tid >> 4) ? 61 : 0;
        R[r * 16 + (tid & 15)] = make_float4(0, 0, 0, 0);
    }
    const float4* bp = (const float4*)(bs + (size_t)f * (C_ * KD * PLANE));
#pragma unroll
    for (int k = 0; k < 4; ++k) {
        const int e = tid + 256 * k;
        if (e < NCH) {
            float4 s = make_float4(0, 0, 0, 0);
#pragma unroll
            for (int s6 = 0; s6 < 6; ++s6) {
                const float4 v = bp[s6 * NCH + e];
                s.x += v.x; s.y += v.y; s.z += v.z; s.w += v.w;
            }
            const int row = e >> 4, col = e & 15;
            R[(row + 1) * 16 + col] = s;
        }
    }
    __syncthreads();
    float4* ob = (float4*)(bb + (size_t)f * PLANE);
#pragma unroll
    for (int k = 0; k < 4; ++k) {
        const int e = tid + 256 * k;
        if (e < NCH) {
            const int row = e >> 4, c4 = e & 15;
            const float4 a = R[row * 16 + c4];
            const float4 m = R[(row + 1) * 16 + c4];
            const float4 d = R[(row + 2) * 16 + c4];
            float4 V;
            V.x = a.x + m.x + d.x; V.y = a.y + m.y + d.y;
            V.z = a.z + m.z + d.z; V.w = a.w + m.w + d.w;
            ob[e] = hsum3(V, c4);
        }
    }
}

// ---------------------------------------------------------------------------
// Kernel 3: main. Block = (b, f, tile of TD douts). Weight in registers,
// reused across the tile. Per dout: elementwise acc = sum_{c,z} S2 .* wt,
// then 3x3 box (vertical via LDS, horizontal via shuffles), + BoxBS,
// *0.25, leaky-relu, float4 store.
// ---------------------------------------------------------------------------
__global__ __launch_bounds__(256) void k_main(const float* __restrict__ s2,
                                              const float* __restrict__ wt,
                                              const float* __restrict__ bb,
                                              float* __restrict__ out) {
    const int bx = blockIdx.x;
    const int tile = bx % NTILE;
    const int f = (bx / NTILE) % F_;
    const int b = bx / (NTILE * F_);
    const int d0 = tile * TD;
    const int tid = threadIdx.x;

    // Weights: 6 slices x 4 chunks of float4 -> 96 VGPRs, loaded once.
    float4 wreg[6][4];
    const float4* wp = (const float4*)(wt + (size_t)f * (C_ * KD * PLANE));
#pragma unroll
    for (int s6 = 0; s6 < 6; ++s6)
#pragma unroll
        for (int k = 0; k < 4; ++k) {
            const int e = tid + 256 * k;
            wreg[s6][k] = (e < NCH) ? wp[s6 * NCH + e] : make_float4(0, 0, 0, 0);
        }

    __shared__ float4 R[62 * 16];
    if (tid < 32) {
        const int r = (tid >> 4) ? 61 : 0;
        R[r * 16 + (tid & 15)] = make_float4(0, 0, 0, 0);
    }

    const float4* s2b = (const float4*)s2 + (size_t)(b * C_) * D_ * NCH;
    const float4* bbp = (const float4*)(bb + (size_t)f * PLANE);
    float* ob = out + (size_t)((b * F_ + f) * Dout_) * PLANE;

    for (int t = 0; t < TD; ++t) {
        const int dout = d0 + t;
        if (dout >= Dout_) break;

        float4 acc[4];
#pragma unroll
        for (int k = 0; k < 4; ++k) acc[k] = make_float4(0, 0, 0, 0);

#pragma unroll
        for (int c = 0; c < C_; ++c)
#pragma unroll
            for (int z = 0; z < KD; ++z) {
                const float4* sp = s2b + (size_t)(c * D_ + dout + z) * NCH;
#pragma unroll
                for (int k = 0; k < 4; ++k) {
                    const int e = tid + 256 * k;
                    if (e < NCH) {
                        const float4 v = sp[e];
                        const float4 w = wreg[c * KD + z][k];
                        acc[k].x += v.x * w.x; acc[k].y += v.y * w.y;
                        acc[k].z += v.z * w.z; acc[k].w += v.w * w.w;
                    }
                }
            }

        if (t > 0) __syncthreads();  // prior iteration's reads must finish
#pragma unroll
        for (int k = 0; k < 4; ++k) {
            const int e = tid + 256 * k;
            if (e < NCH) R[((e >> 4) + 1) * 16 + (e & 15)] = acc[k];
        }
        __syncthreads();

        float4* od4 = (float4*)(ob + (size_t)dout * PLANE);
#pragma unroll
        for (int k = 0; k < 4; ++k) {
            const int e = tid + 256 * k;
            if (e < NCH) {
                const int row = e >> 4, c4 = e & 15;
                const float4 a = R[row * 16 + c4];
                const float4 m = R[(row + 1) * 16 + c4];
                const float4 d = R[(row + 2) * 16 + c4];
                float4 V;
                V.x = a.x + m.x + d.x; V.y = a.y + m.y + d.y;
                V.z = a.z + m.z + d.z; V.w = a.w + m.w + d.w;
                float4 o = hsum3(V, c4);
                const float4 bbv = bbp[e];
                o.x = 0.25f * (o.x + bbv.x); o.y = 0.25f * (o.y + bbv.y);
                o.z = 0.25f * (o.z + bbv.z); o.w = 0.25f * (o.w + bbv.w);
                o.x = (o.x > 0.f) ? o.x : 0.2f * o.x;
                o.y = (o.y > 0.f) ? o.y : 0.2f * o.y;
                o.z = (o.z > 0.f) ? o.z : 0.2f * o.z;
                o.w = (o.w > 0.f) ? o.w : 0.2f * o.w;
                od4[e] = o;
            }
        }
    }
}

extern "C" void kernel_launch(void* const* d_in, const int* in_sizes, int n_in,
                              void* d_out, int out_size, void* d_ws, size_t ws_size,
                              hipStream_t stream) {
    const float* in = (const float*)d_in[0];
    const float* wt = (const float*)d_in[1];
    const float* bs = (const float*)d_in[2];
    float* out = (float*)d_out;

    float* s2 = (float*)d_ws;                  // 23.6 MB
    float* bb = s2 + S2_FLOATS;                // +123 KB

    k_boxbs<<<dim3(F_), dim3(256), 0, stream>>>(bs, bb);
    k_s2<<<dim3(B_ * C_ * D_), dim3(256), 0, stream>>>(in, s2);
    k_main<<<dim3(B_ * F_ * NTILE), dim3(256), 0, stream>>>(s2, wt, bb, out);
}

// Round 3
// 165.231 us; speedup vs baseline: 1.5885x; 1.0193x over previous
//
#include <hip/hip_runtime.h>

// Problem constants:
// inputs: (B=8, C=2, D=96, H=64, W=64) f32
// weight/bias: (F=8, C=2, d=3, h=60, w=64) f32
// out: (B=8, F=8, Dout=94, h=60, w=64) f32
#define B_ 8
#define C_ 2
#define D_ 96
#define H_ 64
#define W_ 64
#define F_ 8
#define KD 3
#define h_ 60
#define Dout_ 94
#define PLANE (h_ * W_)          // 3840 floats
#define NCH (PLANE / 4)          // 960 float4 chunks
#define TD 4                     // douts per block in k_main
#define NTILE ((Dout_ + TD - 1) / TD)  // 24
#define NS2 (B_ * C_ * D_)       // 1536 s2 planes
#define S2_FLOATS ((size_t)NS2 * PLANE)

// Horizontal 3-tap sum via lane shuffles; col4 = position 0..15 within a
// 16-lane row group. Boundary cols contribute zero.
__device__ __forceinline__ float4 hsum3(float4 V, int col4) {
    const int lane = threadIdx.x & 63;
    float lw = __shfl(V.w, (lane + 63) & 63, 64);
    float rx = __shfl(V.x, (lane + 1) & 63, 64);
    if (col4 == 0) lw = 0.f;
    if (col4 == 15) rx = 0.f;
    float4 o;
    o.x = lw + V.x + V.y;
    o.y = V.x + V.y + V.z;
    o.z = V.y + V.z + V.w;
    o.w = V.z + V.w + rx;
    return o;
}

// ---------------------------------------------------------------------------
// Fused prep kernel.
// Blocks 0..NS2-1:            S2[b,c,p] = vertical 5-sum of input plane.
// Blocks NS2..NS2+F_-1:       BoxBS[f]  = Box3x3( sum_{c,z} bias[f,c,z] ).
// ---------------------------------------------------------------------------
__global__ __launch_bounds__(256) void k_prep(const float* __restrict__ in,
                                              const float* __restrict__ bs,
                                              float* __restrict__ s2,
                                              float* __restrict__ bb) {
    const int bx = blockIdx.x;
    const int tid = threadIdx.x;
    __shared__ float4 lds[H_ * 16];  // 16 KB (>= 62*16 used by bias path)

    if (bx < NS2) {
        const float4* ip4 = (const float4*)(in + (size_t)bx * (H_ * W_));
        float4* op4 = (float4*)(s2 + (size_t)bx * PLANE);
#pragma unroll
        for (int k = 0; k < 4; ++k) lds[tid + 256 * k] = ip4[tid + 256 * k];
        __syncthreads();
#pragma unroll
        for (int k = 0; k < 4; ++k) {
            const int e = tid + 256 * k;
            if (e < NCH) {
                const int row = e >> 4, col = e & 15;
                float4 s = lds[row * 16 + col];
#pragma unroll
                for (int j = 1; j < 5; ++j) {
                    const float4 v = lds[(row + j) * 16 + col];
                    s.x += v.x; s.y += v.y; s.z += v.z; s.w += v.w;
                }
                op4[e] = s;
            }
        }
    } else {
        const int f = bx - NS2;
        float4* R = lds;  // rows 0..61, row 0 and 61 zero
        if (tid < 32) {
            const int r = (tid >> 4) ? 61 : 0;
            R[r * 16 + (tid & 15)] = make_float4(0, 0, 0, 0);
        }
        const float4* bp = (const float4*)(bs + (size_t)f * (C_ * KD * PLANE));
#pragma unroll
        for (int k = 0; k < 4; ++k) {
            const int e = tid + 256 * k;
            if (e < NCH) {
                float4 s = make_float4(0, 0, 0, 0);
#pragma unroll
                for (int s6 = 0; s6 < 6; ++s6) {
                    const float4 v = bp[s6 * NCH + e];
                    s.x += v.x; s.y += v.y; s.z += v.z; s.w += v.w;
                }
                R[((e >> 4) + 1) * 16 + (e & 15)] = s;
            }
        }
        __syncthreads();
        float4* ob = (float4*)(bb + (size_t)f * PLANE);
#pragma unroll
        for (int k = 0; k < 4; ++k) {
            const int e = tid + 256 * k;
            if (e < NCH) {
                const int row = e >> 4, c4 = e & 15;
                const float4 a = R[row * 16 + c4];
                const float4 m = R[(row + 1) * 16 + c4];
                const float4 d = R[(row + 2) * 16 + c4];
                float4 V;
                V.x = a.x + m.x + d.x; V.y = a.y + m.y + d.y;
                V.z = a.z + m.z + d.z; V.w = a.w + m.w + d.w;
                ob[e] = hsum3(V, c4);
            }
        }
    }
}

// ---------------------------------------------------------------------------
// Main kernel. Block = (b, f, tile of TD douts). Weight cached in registers.
// Per dout: acc = sum_{c,z} S2 .* wt; 3x3 box: vertical via double-buffered
// LDS (ONE barrier per dout), horizontal via shuffles; +BoxBS, *0.25,
// leaky-relu, float4 store.
// ---------------------------------------------------------------------------
__global__ __launch_bounds__(256) void k_main(const float* __restrict__ s2,
                                              const float* __restrict__ wt,
                                              const float* __restrict__ bb,
                                              float* __restrict__ out) {
    const int bx = blockIdx.x;
    const int tile = bx % NTILE;
    const int f = (bx / NTILE) % F_;
    const int b = bx / (NTILE * F_);
    const int d0 = tile * TD;
    const int tid = threadIdx.x;

    float4 wreg[6][4];
    const float4* wp = (const float4*)(wt + (size_t)f * (C_ * KD * PLANE));
#pragma unroll
    for (int s6 = 0; s6 < 6; ++s6)
#pragma unroll
        for (int k = 0; k < 4; ++k) {
            const int e = tid + 256 * k;
            wreg[s6][k] = (e < NCH) ? wp[s6 * NCH + e] : make_float4(0, 0, 0, 0);
        }

    __shared__ float4 R[2][62 * 16];  // 31744 B, double-buffered
    if (tid < 32) {
        const int r = (tid >> 4) ? 61 : 0;
        R[0][r * 16 + (tid & 15)] = make_float4(0, 0, 0, 0);
        R[1][r * 16 + (tid & 15)] = make_float4(0, 0, 0, 0);
    }

    const float4* s2b = (const float4*)s2 + (size_t)(b * C_) * D_ * NCH;
    const float4* bbp = (const float4*)(bb + (size_t)f * PLANE);
    float* ob = out + (size_t)((b * F_ + f) * Dout_) * PLANE;

#pragma unroll
    for (int t = 0; t < TD; ++t) {
        const int dout = d0 + t;

        float4 acc[4];
#pragma unroll
        for (int k = 0; k < 4; ++k) acc[k] = make_float4(0, 0, 0, 0);

#pragma unroll
        for (int c = 0; c < C_; ++c)
#pragma unroll
            for (int z = 0; z < KD; ++z) {
                int p = dout + z; if (p > D_ - 1) p = D_ - 1;  // clamp (tail tile)
                const float4* sp = s2b + (size_t)(c * D_ + p) * NCH;
#pragma unroll
                for (int k = 0; k < 4; ++k) {
                    const int e = tid + 256 * k;
                    if (e < NCH) {
                        const float4 v = sp[e];
                        const float4 w = wreg[c * KD + z][k];
                        acc[k].x += v.x * w.x; acc[k].y += v.y * w.y;
                        acc[k].z += v.z * w.z; acc[k].w += v.w * w.w;
                    }
                }
            }

        float4* Rb = R[t & 1];
#pragma unroll
        for (int k = 0; k < 4; ++k) {
            const int e = tid + 256 * k;
            if (e < NCH) Rb[((e >> 4) + 1) * 16 + (e & 15)] = acc[k];
        }
        __syncthreads();   // the single barrier per dout

        if (dout < Dout_) {
            float4* od4 = (float4*)(ob + (size_t)dout * PLANE);
#pragma unroll
            for (int k = 0; k < 4; ++k) {
                const int e = tid + 256 * k;
                if (e < NCH) {
                    const int row = e >> 4, c4 = e & 15;
                    const float4 a = Rb[row * 16 + c4];
                    const float4 m = Rb[(row + 1) * 16 + c4];
                    const float4 d = Rb[(row + 2) * 16 + c4];
                    float4 V;
                    V.x = a.x + m.x + d.x; V.y = a.y + m.y + d.y;
                    V.z = a.z + m.z + d.z; V.w = a.w + m.w + d.w;
                    float4 o = hsum3(V, c4);
                    const float4 bbv = bbp[e];
                    o.x = 0.25f * (o.x + bbv.x); o.y = 0.25f * (o.y + bbv.y);
                    o.z = 0.25f * (o.z + bbv.z); o.w = 0.25f * (o.w + bbv.w);
                    o.x = (o.x > 0.f) ? o.x : 0.2f * o.x;
                    o.y = (o.y > 0.f) ? o.y : 0.2f * o.y;
                    o.z = (o.z > 0.f) ? o.z : 0.2f * o.z;
                    o.w = (o.w > 0.f) ? o.w : 0.2f * o.w;
                    od4[e] = o;
                }
            }
        }
    }
}

extern "C" void kernel_launch(void* const* d_in, const int* in_sizes, int n_in,
                              void* d_out, int out_size, void* d_ws, size_t ws_size,
                              hipStream_t stream) {
    const float* in = (const float*)d_in[0];
    const float* wt = (const float*)d_in[1];
    const float* bs = (const float*)d_in[2];
    float* out = (float*)d_out;

    float* s2 = (float*)d_ws;
    float* bb = s2 + S2_FLOATS;

    k_prep<<<dim3(NS2 + F_), dim3(256), 0, stream>>>(in, bs, s2, bb);
    k_main<<<dim3(B_ * F_ * NTILE), dim3(256), 0, stream>>>(s2, wt, bb, out);
}